// Round 1
// baseline (44155.847 us; speedup 1.0000x reference)
//
#include <hip/hip_runtime.h>

// Tacotron-2 style decoder, B=16, T=256, DEC=1024, ENC=256, MEL=80, ATT=128.
// Structure:
//   - All teacher-forced inputs known upfront -> prenet / q-proj / proc_mem as parallel GEMMs.
//   - Attention chain decoupled from LSTM state; per step: kernel A (attention energies +
//     softmax partials + LSTM2 of step t-1) and kernel B (LSTM1 of step t + housekeeping).
//   - Wave lane mapping (b=lane>>2, gate=lane&3): 16 batch lanes read identical weight
//     addresses (merged broadcast -> weights fetched once per wave, no 16x batch redundancy);
//     all 4 gates of one (b,d) are in one wave -> state update via __shfl, no extra sync.
//   - Unnormalized softmax (|e| small, no max needed): exp + atomic sum + atomic uctx;
//     1/sum folded into consumers. Parity double-buffering for w_exp/sum/uctx/h1/h2.
//   - mel/stop projection batched at the end from stored h2_all.

namespace {

constexpr int TT = 256, BB = 16, LL = 256, MELD = 80, ATTD = 128, FILTD = 32, KC = 31;

struct Args {
  const float *enc, *spe, *mels;
  const float *Wpre1, *bpre1, *Wpre2, *bpre2, *Wsp, *bsp;
  const float *Wq, *Wm, *Wconv, *Wloc, *vatt;
  const float *Wih1, *Whh1, *bih1, *bhh1;
  const float *Wih2, *Whh2, *bih2, *bhh2;
  const float *Wmel, *bmel, *Wstop, *bstop;
  float *p, *X, *qp2, *pm2, *prevmel;
  float *h1a, *h1b, *c1, *h2a, *h2b, *c2;
  float *cum, *wexp, *uctx, *sum, *spkvec, *spkq;
  float *out;
};

__device__ __forceinline__ float fast_tanh(float x) {
  float ax = fabsf(x);
  float e = __expf(-2.f * ax);
  float t = (1.f - e) / (1.f + e);
  return copysignf(t, x);
}
__device__ __forceinline__ float fast_sig(float x) { return 1.f / (1.f + __expf(-x)); }

// zero the state region; sum[1][b] must start at 1.0 (divisor for the zero step-(-1) weights)
__global__ void k_init(float* base, int n, int s1off) {
  int i = blockIdx.x * blockDim.x + threadIdx.x;
  if (i < n) base[i] = (i >= s1off && i < s1off + 16) ? 1.f : 0.f;
}

__global__ void k_prevmel(Args a) {
  int i = blockIdx.x * blockDim.x + threadIdx.x;  // (t*16+b)*80+m
  if (i >= TT * BB * MELD) return;
  int m = i % MELD;
  int tb = i / MELD;
  int b = tb & 15, t = tb >> 4;
  a.prevmel[i] = (t == 0) ? 0.f : a.mels[(b * TT + t) * MELD + m];
}

__global__ void k_spkvec(Args a) {
  int i = blockIdx.x * blockDim.x + threadIdx.x;
  if (i >= BB * 1024) return;
  int b = i >> 10, j = i & 1023;
  const float* x = a.spe + b * 256;
  const float* w = a.Wsp + j * 256;
  float s = a.bsp[j];
  for (int k = 0; k < 256; ++k) s += x[k] * w[k];
  a.spkvec[i] = s;
}

__global__ void k_spkq(Args a) {
  int i = blockIdx.x * blockDim.x + threadIdx.x;
  if (i >= BB * ATTD) return;
  int b = i >> 7, q = i & 127;
  const float* x = a.spkvec + b * 1024;
  const float* w = a.Wq + q * 1024;
  float s = 0.f;
  for (int k = 0; k < 1024; ++k) s += x[k] * w[k];
  a.spkq[i] = s;
}

// C[M,N] = act(A[M,K] @ B[N,K]^T + bias[N]); 64x64 tile, 4x4 per thread.
__global__ __launch_bounds__(256) void k_gemm(const float* A, const float* Bm, const float* bias,
                                              float* C, int M, int N, int K, int act) {
  __shared__ float As[16][65];
  __shared__ float Bs[16][65];
  int bm = blockIdx.y * 64, bn = blockIdx.x * 64;
  int tid = threadIdx.x;
  int tm = (tid >> 4) * 4, tn = (tid & 15) * 4;
  float acc[4][4] = {};
  for (int k0 = 0; k0 < K; k0 += 16) {
    for (int i = tid; i < 1024; i += 256) {
      int m = i >> 4, kk = i & 15;
      As[kk][m] = A[(size_t)(bm + m) * K + k0 + kk];
      Bs[kk][m] = Bm[(size_t)(bn + m) * K + k0 + kk];
    }
    __syncthreads();
#pragma unroll
    for (int kk = 0; kk < 16; ++kk) {
      float a0 = As[kk][tm], a1 = As[kk][tm + 1], a2 = As[kk][tm + 2], a3 = As[kk][tm + 3];
      float b0 = Bs[kk][tn], b1 = Bs[kk][tn + 1], b2 = Bs[kk][tn + 2], b3 = Bs[kk][tn + 3];
      acc[0][0] += a0 * b0; acc[0][1] += a0 * b1; acc[0][2] += a0 * b2; acc[0][3] += a0 * b3;
      acc[1][0] += a1 * b0; acc[1][1] += a1 * b1; acc[1][2] += a1 * b2; acc[1][3] += a1 * b3;
      acc[2][0] += a2 * b0; acc[2][1] += a2 * b1; acc[2][2] += a2 * b2; acc[2][3] += a2 * b3;
      acc[3][0] += a3 * b0; acc[3][1] += a3 * b1; acc[3][2] += a3 * b2; acc[3][3] += a3 * b3;
    }
    __syncthreads();
  }
  for (int i = 0; i < 4; ++i)
    for (int j = 0; j < 4; ++j) {
      float v = acc[i][j];
      if (bias) v += bias[bn + tn + j];
      if (act == 1) v = fmaxf(v, 0.f);
      C[(size_t)(bm + tm + i) * N + bn + tn + j] = v;
    }
}

__global__ void k_pm_transpose(Args a) {
  int i = blockIdx.x * blockDim.x + threadIdx.x;  // dest (b*128+q)*256 + l
  if (i >= BB * ATTD * LL) return;
  int l = i & 255;
  int rest = i >> 8;
  int q = rest & 127, b = rest >> 7;
  a.pm2[i] = a.X[(size_t)((b << 8) + l) * 128 + q];
}

__global__ void k_addspkq(Args a) {
  int i = blockIdx.x * blockDim.x + threadIdx.x;
  if (i >= TT * BB * ATTD) return;
  int q = i & 127, b = (i >> 7) & 15;
  a.qp2[i] += a.spkq[b * 128 + q];
}

// Kernel A(t): attention energies+softmax partials for step t (if do_attn),
//              plus full LSTM2 for step t-1 (if do_l2).
__global__ __launch_bounds__(256) void k_step_a(Args a, int t, int do_attn, int do_l2) {
  const int wg = blockIdx.x, tid = threadIdx.x;
  if (do_attn) {
    __shared__ float loc[2][64];
    __shared__ float F[FILTD][17];
    __shared__ float expv[16];
    const int b = wg >> 4, c = wg & 15, l0 = c << 4;
    const int cur = t & 1, prv = cur ^ 1;
    const float inv_ps = 1.f / a.sum[prv * 16 + b];
    if (tid < 64) {
      int lp = l0 - 16 + tid;
      bool ok = (lp >= 0 && lp < LL);
      loc[0][tid] = ok ? a.wexp[prv * 4096 + b * 256 + lp] * inv_ps : 0.f;
      loc[1][tid] = ok ? a.cum[b * 256 + lp] : 0.f;
    }
    __syncthreads();
    // location conv: F[fc][ll] for 16 l's of this chunk, padded window in LDS
    for (int idx = tid; idx < FILTD * 16; idx += 256) {
      int fc = idx >> 4, ll = idx & 15;
      const float* w = a.Wconv + fc * 62;
      float s = 0.f;
#pragma unroll
      for (int k = 0; k < KC; ++k) {
        s += w[k] * loc[0][ll + k + 1];
        s += w[31 + k] * loc[1][ll + k + 1];
      }
      F[fc][ll] = s;
    }
    __syncthreads();
    {
      const int ll = tid >> 4, ag = tid & 15;
      const int l = l0 + ll;
      const float* qpb = a.qp2 + (size_t)((t << 4) + b) * 128;
      const float* pmb = a.pm2 + (size_t)b * 128 * 256;
      float s = 0.f;
      for (int q = ag * 8; q < ag * 8 + 8; ++q) {
        float x = qpb[q] + pmb[q * 256 + l];
        const float* wl = a.Wloc + q * 32;
#pragma unroll
        for (int fc = 0; fc < FILTD; ++fc) x += wl[fc] * F[fc][ll];
        s += a.vatt[q] * fast_tanh(x);
      }
      s += __shfl_down(s, 8, 16);
      s += __shfl_down(s, 4, 16);
      s += __shfl_down(s, 2, 16);
      s += __shfl_down(s, 1, 16);
      if (ag == 0) {
        float ex = __expf(s);  // |e| <= ~5 so no max-subtraction needed
        expv[ll] = ex;
        a.wexp[cur * 4096 + b * 256 + l] = ex;
      }
    }
    __syncthreads();
    if (tid == 0) {
      float s = 0.f;
#pragma unroll
      for (int i = 0; i < 16; ++i) s += expv[i];
      atomicAdd(&a.sum[cur * 16 + b], s);
    }
    {
      float s = 0.f;
      const float* eb = a.enc + (size_t)((b << 8) + l0) * 256 + tid;
#pragma unroll
      for (int ll = 0; ll < 16; ++ll) s += expv[ll] * eb[ll * 256];
      atomicAdd(&a.uctx[cur * 4096 + b * 256 + tid], s);
    }
  }
  if (do_l2) {
    const int s_ = t - 1;
    const int wv = tid >> 6, lane = tid & 63;
    const int d = (wg << 2) + wv;
    const int b = lane >> 2, g = lane & 3;
    const int j = (g << 10) + d;
    const float* h1r = (s_ & 1) ? a.h1b : a.h1a;   // h1_{s}, written by KB(s) at parity s&1
    const float* h2r = (s_ & 1) ? a.h2a : a.h2b;   // h2_{s-1} at parity (s-1)&1
    float* h2w = (s_ & 1) ? a.h2b : a.h2a;         // h2_s at parity s&1
    float acc = a.bih2[j] + a.bhh2[j];
    const float* wi = a.Wih2 + (size_t)j * 1024;
    const float* wh = a.Whh2 + (size_t)j * 1024;
    const float* x1 = h1r + b * 1024;
    const float* x2 = h2r + b * 1024;
#pragma unroll 4
    for (int k = 0; k < 1024; k += 4) {
      float4 w4 = *reinterpret_cast<const float4*>(wi + k);
      float4 v4 = *reinterpret_cast<const float4*>(x1 + k);
      acc += w4.x * v4.x + w4.y * v4.y + w4.z * v4.z + w4.w * v4.w;
    }
#pragma unroll 4
    for (int k = 0; k < 1024; k += 4) {
      float4 w4 = *reinterpret_cast<const float4*>(wh + k);
      float4 v4 = *reinterpret_cast<const float4*>(x2 + k);
      acc += w4.x * v4.x + w4.y * v4.y + w4.z * v4.z + w4.w * v4.w;
    }
    int base = lane & ~3;
    float gi = __shfl(acc, base, 64);
    float gf = __shfl(acc, base + 1, 64);
    float gg = __shfl(acc, base + 2, 64);
    float go = __shfl(acc, base + 3, 64);
    if (g == 0) {
      float co = a.c2[b * 1024 + d];
      float cn = fast_sig(gf) * co + fast_sig(gi) * fast_tanh(gg);
      float hn = fast_sig(go) * fast_tanh(cn);
      a.c2[b * 1024 + d] = cn;
      h2w[b * 1024 + d] = hn;
      a.X[(size_t)(s_ * 16 + b) * 1024 + d] = hn;  // h2_all for final projection
    }
  }
}

// Kernel B(t): LSTM1 for step t (+ cum_w update, next-parity zeroing).
__global__ __launch_bounds__(256) void k_step_b(Args a, int t) {
  const int wg = blockIdx.x, tid = threadIdx.x;
  const int cur = t & 1, nxt = cur ^ 1;
  if (wg < 16) {
    float is = 1.f / a.sum[cur * 16 + wg];
    a.cum[wg * 256 + tid] += a.wexp[cur * 4096 + wg * 256 + tid] * is;
  } else if (wg < 32) {
    int b = wg - 16;
    a.uctx[nxt * 4096 + b * 256 + tid] = 0.f;
    if (wg == 16 && tid < 16) a.sum[nxt * 16 + tid] = 0.f;
  }
  const int wv = tid >> 6, lane = tid & 63;
  const int d = (wg << 2) + wv;
  const int b = lane >> 2, g = lane & 3;
  const int j = (g << 10) + d;
  float acc = a.bih1[j] + a.bhh1[j];
  const float* wi = a.Wih1 + (size_t)j * 1280;
  const float* pb = a.p + (size_t)(t * 16 + b) * 1024;
#pragma unroll 4
  for (int k = 0; k < 1024; k += 4) {
    float4 w4 = *reinterpret_cast<const float4*>(wi + k);
    float4 v4 = *reinterpret_cast<const float4*>(pb + k);
    acc += w4.x * v4.x + w4.y * v4.y + w4.z * v4.z + w4.w * v4.w;
  }
  {
    float s2 = 0.f;
    const float* uc = a.uctx + cur * 4096 + b * 256;
    const float* wc = wi + 1024;
#pragma unroll 4
    for (int k = 0; k < 256; k += 4) {
      float4 w4 = *reinterpret_cast<const float4*>(wc + k);
      float4 v4 = *reinterpret_cast<const float4*>(uc + k);
      s2 += w4.x * v4.x + w4.y * v4.y + w4.z * v4.z + w4.w * v4.w;
    }
    acc += s2 * (1.f / a.sum[cur * 16 + b]);  // normalize ctx here
  }
  const float* h1r = (t & 1) ? a.h1a : a.h1b;  // h1_{t-1} at parity (t-1)&1
  float* h1w = (t & 1) ? a.h1b : a.h1a;        // h1_t at parity t&1
  const float* wh = a.Whh1 + (size_t)j * 1024;
  const float* hb = h1r + b * 1024;
#pragma unroll 4
  for (int k = 0; k < 1024; k += 4) {
    float4 w4 = *reinterpret_cast<const float4*>(wh + k);
    float4 v4 = *reinterpret_cast<const float4*>(hb + k);
    acc += w4.x * v4.x + w4.y * v4.y + w4.z * v4.z + w4.w * v4.w;
  }
  int base = lane & ~3;
  float gi = __shfl(acc, base, 64);
  float gf = __shfl(acc, base + 1, 64);
  float gg = __shfl(acc, base + 2, 64);
  float go = __shfl(acc, base + 3, 64);
  if (g == 0) {
    float co = a.c1[b * 1024 + d];
    float cn = fast_sig(gf) * co + fast_sig(gi) * fast_tanh(gg);
    float hn = fast_sig(go) * fast_tanh(cn);
    a.c1[b * 1024 + d] = cn;
    h1w[b * 1024 + d] = hn;
  }
}

__global__ __launch_bounds__(128) void k_out(Args a) {
  __shared__ float hs[1024];
  int tb = blockIdx.x;
  int t = tb >> 4, b = tb & 15;
  const float* h = a.X + (size_t)tb * 1024;
  for (int i = threadIdx.x; i < 1024; i += 128) hs[i] = h[i];
  __syncthreads();
  int m = threadIdx.x;
  if (m < 80) {
    const float* w = a.Wmel + m * 1024;
    float s = a.bmel[m];
    for (int k = 0; k < 1024; ++k) s += w[k] * hs[k];
    a.out[(size_t)(b * 256 + t) * 80 + m] = s;
  } else if (m == 80) {
    float s = a.bstop[0];
    for (int k = 0; k < 1024; ++k) s += a.Wstop[k] * hs[k];
    a.out[327680 + b * 256 + t] = fast_sig(s);
  }
}

}  // namespace

extern "C" void kernel_launch(void* const* d_in, const int* in_sizes, int n_in,
                              void* d_out, int out_size, void* d_ws, size_t ws_size,
                              hipStream_t stream) {
  float* ws = (float*)d_ws;
  Args a;
  a.enc = (const float*)d_in[0];
  a.spe = (const float*)d_in[1];
  a.mels = (const float*)d_in[2];
  a.Wpre1 = (const float*)d_in[3];  a.bpre1 = (const float*)d_in[4];
  a.Wpre2 = (const float*)d_in[5];  a.bpre2 = (const float*)d_in[6];
  a.Wsp = (const float*)d_in[7];    a.bsp = (const float*)d_in[8];
  a.Wq = (const float*)d_in[9];     a.Wm = (const float*)d_in[10];
  a.Wconv = (const float*)d_in[11]; a.Wloc = (const float*)d_in[12];
  a.vatt = (const float*)d_in[13];
  a.Wih1 = (const float*)d_in[14];  a.Whh1 = (const float*)d_in[15];
  a.bih1 = (const float*)d_in[16];  a.bhh1 = (const float*)d_in[17];
  a.Wih2 = (const float*)d_in[18];  a.Whh2 = (const float*)d_in[19];
  a.bih2 = (const float*)d_in[20];  a.bhh2 = (const float*)d_in[21];
  a.Wmel = (const float*)d_in[22];  a.bmel = (const float*)d_in[23];
  a.Wstop = (const float*)d_in[24]; a.bstop = (const float*)d_in[25];

  // ws layout (floats); total ~9.91M floats = ~39.6 MB
  a.p       = ws + 0;        // 4096x1024
  a.X       = ws + 4194304;  // prenet hidden -> pm temp -> h2_all (16 MB, time-multiplexed)
  a.qp2     = ws + 8388608;  // 4096x128
  a.pm2     = ws + 8912896;  // 16x128x256
  a.prevmel = ws + 9437184;  // 4096x80
  a.h1a     = ws + 9764864;  a.h1b = ws + 9781248;
  a.c1      = ws + 9797632;
  a.h2a     = ws + 9814016;  a.h2b = ws + 9830400;
  a.c2      = ws + 9846784;
  a.cum     = ws + 9863168;  // 16x256
  a.wexp    = ws + 9867264;  // 2x16x256
  a.uctx    = ws + 9875456;  // 2x16x256
  a.sum     = ws + 9883648;  // 2x16
  a.spkvec  = ws + 9883680;  // 16x1024
  a.spkq    = ws + 9900064;  // 16x128
  a.out = (float*)d_out;

  // init state region [h1a .. end); sum[1][*] = 1.0 (offset 118800 within region)
  k_init<<<(137248 + 255) / 256, 256, 0, stream>>>(ws + 9764864, 137248, 118800);
  k_prevmel<<<(TT * BB * MELD + 255) / 256, 256, 0, stream>>>(a);
  k_spkvec<<<(BB * 1024 + 255) / 256, 256, 0, stream>>>(a);
  k_spkq<<<(BB * ATTD + 255) / 256, 256, 0, stream>>>(a);

  // prenet1 -> X (temp), prenet2 -> p
  k_gemm<<<dim3(1024 / 64, 4096 / 64), 256, 0, stream>>>(a.prevmel, a.Wpre1, a.bpre1, a.X, 4096, 1024, 80, 1);
  k_gemm<<<dim3(1024 / 64, 4096 / 64), 256, 0, stream>>>(a.X, a.Wpre2, a.bpre2, a.p, 4096, 1024, 1024, 1);
  // qp2 = p @ Wq^T (+ spkq)
  k_gemm<<<dim3(128 / 64, 4096 / 64), 256, 0, stream>>>(a.p, a.Wq, nullptr, a.qp2, 4096, 128, 1024, 0);
  k_addspkq<<<(TT * BB * ATTD + 255) / 256, 256, 0, stream>>>(a);
  // proc_mem = enc @ Wm^T into X temp, then transpose to [b][a][l]
  k_gemm<<<dim3(128 / 64, 4096 / 64), 256, 0, stream>>>(a.enc, a.Wm, nullptr, a.X, 4096, 128, 256, 0);
  k_pm_transpose<<<(BB * ATTD * LL + 255) / 256, 256, 0, stream>>>(a);

  for (int t = 0; t < 256; ++t) {
    k_step_a<<<256, 256, 0, stream>>>(a, t, 1, t > 0 ? 1 : 0);
    k_step_b<<<256, 256, 0, stream>>>(a, t);
  }
  k_step_a<<<256, 256, 0, stream>>>(a, 256, 0, 1);  // final LSTM2 for step 255

  k_out<<<4096, 128, 0, stream>>>(a);
}

// Round 2
// 17935.457 us; speedup vs baseline: 2.4619x; 2.4619x over previous
//
#include <hip/hip_runtime.h>

// Tacotron-2 style decoder, B=16, T=256, DEC=1024, ENC=256, MEL=80, ATT=128.
// R2 restructure:
//  - LSTM gemv as K-lane-split skinny GEMM: wave = 4 rows (one gate) x 16 batch,
//    64 lanes split K -> weight loads are full-wave coalesced dwordx4 (1KB/instr).
//    x (inputs|ctx|h) staged in LDS per WG (~144KB); partial sums reduced via LDS
//    transpose; state update done in-WG (tile = 4 d x 4 gates x 16 b).
//  - Kernel A(t): attention chunk (t) then LSTM2(t-1) in the same WGs.
//    Kernel B(t): LSTM1(t) + housekeeping WGs. 2 launches/step.
//  - Prenet/q-proj/proc_mem/mel-out as 128x64-tile fp32 GEMMs (float4 LDS).

namespace {

constexpr int TT = 256, BB = 16, LL = 256, MELD = 80, ATTD = 128, FILTD = 32, KC = 31;
constexpr int P1 = 2308;  // LSTM1 xs pitch (2304+4)
constexpr int P2 = 2052;  // LSTM2 xs pitch (2048+4)

struct Args {
  const float *enc, *spe, *mels;
  const float *Wpre1, *bpre1, *Wpre2, *bpre2, *Wsp, *bsp;
  const float *Wq, *Wm, *Wconv, *Wloc, *vatt;
  const float *Wih1, *Whh1, *bih1, *bhh1;
  const float *Wih2, *Whh2, *bih2, *bhh2;
  const float *Wmel, *bmel, *Wstop, *bstop;
  float *p, *X, *qp2, *pm2, *prevmel;
  float *h1a, *h1b, *c1, *h2a, *h2b, *c2;
  float *cum, *wexp, *uctx, *sum, *spkvec, *spkq;
  float *W81, *b81, *tmp;
  float *out;
};

__device__ __forceinline__ float fast_tanh(float x) {
  float ax = fabsf(x);
  float e = __expf(-2.f * ax);
  float t = (1.f - e) / (1.f + e);
  return copysignf(t, x);
}
__device__ __forceinline__ float fast_sig(float x) { return 1.f / (1.f + __expf(-x)); }

// zero state region; sum[1][b] = 1.0 (divisor for the zero step-(-1) weights)
__global__ void k_init(float* base, int n, int s1off) {
  int i = blockIdx.x * blockDim.x + threadIdx.x;
  if (i < n) base[i] = (i >= s1off && i < s1off + 16) ? 1.f : 0.f;
}

__global__ void k_prevmel(Args a) {
  int i = blockIdx.x * blockDim.x + threadIdx.x;  // (t*16+b)*80+m
  if (i >= TT * BB * MELD) return;
  int m = i % MELD;
  int tb = i / MELD;
  int b = tb & 15, t = tb >> 4;
  a.prevmel[i] = (t == 0) ? 0.f : a.mels[(b * TT + t) * MELD + m];
}

__global__ void k_spkvec(Args a) {
  int i = blockIdx.x * blockDim.x + threadIdx.x;
  if (i >= BB * 1024) return;
  int b = i >> 10, j = i & 1023;
  const float* x = a.spe + b * 256;
  const float* w = a.Wsp + j * 256;
  float s = a.bsp[j];
  for (int k = 0; k < 256; ++k) s += x[k] * w[k];
  a.spkvec[i] = s;
}

__global__ void k_spkq(Args a) {
  int i = blockIdx.x * blockDim.x + threadIdx.x;
  if (i >= BB * ATTD) return;
  int b = i >> 7, q = i & 127;
  const float* x = a.spkvec + b * 1024;
  const float* w = a.Wq + q * 1024;
  float s = 0.f;
  for (int k = 0; k < 1024; ++k) s += x[k] * w[k];
  a.spkq[i] = s;
}

__global__ void k_prep81(Args a) {
  int i = blockIdx.x * blockDim.x + threadIdx.x;
  if (i < 81 * 1024) {
    int r = i >> 10, k = i & 1023;
    a.W81[i] = (r < 80) ? a.Wmel[r * 1024 + k] : a.Wstop[k];
  }
  if (i < 81) a.b81[i] = (i < 80) ? a.bmel[i] : a.bstop[0];
}

// C[M,N] = act(A[M,K] @ B[N,K]^T + bias[N]); 128x64 tile, 8x4 per thread, float4 LDS.
// Requires M%128==0, N%64==0, K%16==0.
__global__ __launch_bounds__(256) void k_gemm(const float* __restrict__ A,
                                              const float* __restrict__ Bm,
                                              const float* __restrict__ bias,
                                              float* __restrict__ C,
                                              int M, int N, int K, int act) {
  __shared__ __align__(16) float As[16][132];
  __shared__ __align__(16) float Bs[16][68];
  const int bm = blockIdx.y * 128, bn = blockIdx.x * 64;
  const int tid = threadIdx.x;
  const int tm = (tid >> 4) * 8, tn = (tid & 15) * 4;
  float acc[8][4] = {};
  for (int k0 = 0; k0 < K; k0 += 16) {
    for (int i = tid; i < 512; i += 256) {
      int m = i >> 2, kq = i & 3;
      float4 v = *(const float4*)(A + (size_t)(bm + m) * K + k0 + kq * 4);
      As[kq * 4 + 0][m] = v.x; As[kq * 4 + 1][m] = v.y;
      As[kq * 4 + 2][m] = v.z; As[kq * 4 + 3][m] = v.w;
    }
    {
      int m = tid >> 2, kq = tid & 3;
      float4 v = *(const float4*)(Bm + (size_t)(bn + m) * K + k0 + kq * 4);
      Bs[kq * 4 + 0][m] = v.x; Bs[kq * 4 + 1][m] = v.y;
      Bs[kq * 4 + 2][m] = v.z; Bs[kq * 4 + 3][m] = v.w;
    }
    __syncthreads();
#pragma unroll
    for (int kk = 0; kk < 16; ++kk) {
      float4 a0 = *(const float4*)&As[kk][tm];
      float4 a1 = *(const float4*)&As[kk][tm + 4];
      float4 b0 = *(const float4*)&Bs[kk][tn];
      float av[8] = {a0.x, a0.y, a0.z, a0.w, a1.x, a1.y, a1.z, a1.w};
      float bv[4] = {b0.x, b0.y, b0.z, b0.w};
#pragma unroll
      for (int i = 0; i < 8; ++i)
#pragma unroll
        for (int j = 0; j < 4; ++j) acc[i][j] += av[i] * bv[j];
    }
    __syncthreads();
  }
#pragma unroll
  for (int i = 0; i < 8; ++i)
#pragma unroll
    for (int j = 0; j < 4; ++j) {
      float v = acc[i][j];
      if (bias) v += bias[bn + tn + j];
      if (act == 1) v = fmaxf(v, 0.f);
      C[(size_t)(bm + tm + i) * N + bn + tn + j] = v;
    }
}

__global__ void k_pm_transpose(Args a) {
  int i = blockIdx.x * blockDim.x + threadIdx.x;  // dest (b*128+q)*256 + l
  if (i >= BB * ATTD * LL) return;
  int l = i & 255;
  int rest = i >> 8;
  int q = rest & 127, b = rest >> 7;
  a.pm2[i] = a.X[(size_t)((b << 8) + l) * 128 + q];
}

__global__ void k_addspkq(Args a) {
  int i = blockIdx.x * blockDim.x + threadIdx.x;
  if (i >= TT * BB * ATTD) return;
  int q = i & 127, b = (i >> 7) & 15;
  a.qp2[i] += a.spkq[b * 128 + q];
}

// ---- Kernel A(t): attention for step t (do_attn), then LSTM2 for step t-1 (do_l2).
__global__ __launch_bounds__(256) void k_step_a(Args a, int t, int do_attn, int do_l2) {
  __shared__ __align__(16) float xs[16 * P2];   // 131,328 B; attn overlays its scratch here
  __shared__ float gbuf[16][20];
  const int wg = blockIdx.x, tid = threadIdx.x;

  if (do_attn) {
    float* loc0 = xs;          // 64
    float* loc1 = xs + 64;     // 64
    float* F    = xs + 128;    // 32 x 17 = 544
    float* expv = xs + 672;    // 16
    const int b = wg >> 4, c = wg & 15, l0 = c << 4;
    const int cur = t & 1, prv = cur ^ 1;
    const float inv_ps = 1.f / a.sum[prv * 16 + b];
    if (tid < 64) {
      int lp = l0 - 16 + tid;
      bool ok = (lp >= 0 && lp < LL);
      loc0[tid] = ok ? a.wexp[prv * 4096 + b * 256 + lp] * inv_ps : 0.f;
      loc1[tid] = ok ? a.cum[b * 256 + lp] : 0.f;
    }
    __syncthreads();
    for (int idx = tid; idx < FILTD * 16; idx += 256) {
      int fc = idx >> 4, ll = idx & 15;
      const float* w = a.Wconv + fc * 62;
      float s = 0.f;
#pragma unroll
      for (int k = 0; k < KC; ++k) {
        s += w[k] * loc0[ll + k + 1];
        s += w[31 + k] * loc1[ll + k + 1];
      }
      F[fc * 17 + ll] = s;
    }
    __syncthreads();
    {
      const int ll = tid >> 4, ag = tid & 15;
      const int l = l0 + ll;
      const float* qpb = a.qp2 + (size_t)((t << 4) + b) * 128;
      const float* pmb = a.pm2 + (size_t)b * 128 * 256;
      float s = 0.f;
      for (int q = ag * 8; q < ag * 8 + 8; ++q) {
        float x = qpb[q] + pmb[q * 256 + l];
        const float* wl = a.Wloc + q * 32;
#pragma unroll
        for (int fc = 0; fc < FILTD; ++fc) x += wl[fc] * F[fc * 17 + ll];
        s += a.vatt[q] * fast_tanh(x);
      }
      s += __shfl_down(s, 8, 16);
      s += __shfl_down(s, 4, 16);
      s += __shfl_down(s, 2, 16);
      s += __shfl_down(s, 1, 16);
      if (ag == 0) {
        float ex = __expf(s);  // |e| small -> no max-subtraction needed
        expv[ll] = ex;
        a.wexp[cur * 4096 + b * 256 + l] = ex;
      }
    }
    __syncthreads();
    if (tid == 0) {
      float s = 0.f;
#pragma unroll
      for (int i = 0; i < 16; ++i) s += expv[i];
      atomicAdd(&a.sum[cur * 16 + b], s);
    }
    {
      float s = 0.f;
      const float* eb = a.enc + (size_t)((b << 8) + l0) * 256 + tid;
#pragma unroll
      for (int ll = 0; ll < 16; ++ll) s += expv[ll] * eb[ll * 256];
      atomicAdd(&a.uctx[cur * 4096 + b * 256 + tid], s);
    }
    __syncthreads();  // done with xs overlay
  }

  if (do_l2) {
    const int s_ = t - 1;
    const float* h1r = (s_ & 1) ? a.h1b : a.h1a;  // h1(s)
    const float* h2r = (s_ & 1) ? a.h2a : a.h2b;  // h2(s-1)
    float* h2w = (s_ & 1) ? a.h2b : a.h2a;        // h2(s)
    for (int i = tid; i < 16 * 1024; i += 256) {
      int b = i >> 10, k = i & 1023;
      xs[b * P2 + k] = h1r[i];
      xs[b * P2 + 1024 + k] = h2r[i];
    }
    __syncthreads();
    const int wv = tid >> 6, lane = tid & 63;
    const int d0 = wg * 4;
    const int kl = lane * 4;
    // wave wv = gate wv; rows = wv*1024 + d0 + q, q=0..3
    const float* rih[4];
    const float* rhh[4];
#pragma unroll
    for (int q = 0; q < 4; ++q) {
      int row = wv * 1024 + d0 + q;
      rih[q] = a.Wih2 + (size_t)row * 1024;
      rhh[q] = a.Whh2 + (size_t)row * 1024;
    }
    float acc[4][16];
#pragma unroll
    for (int q = 0; q < 4; ++q)
#pragma unroll
      for (int b = 0; b < 16; ++b) acc[q][b] = 0.f;
    float4 wreg[4];
#pragma unroll
    for (int q = 0; q < 4; ++q) wreg[q] = *(const float4*)(rih[q] + kl);
    for (int kb = 0; kb < 8; ++kb) {
      float4 wc[4];
#pragma unroll
      for (int q = 0; q < 4; ++q) wc[q] = wreg[q];
      if (kb + 1 < 8) {
        int kn = (kb + 1) * 256 + kl;
#pragma unroll
        for (int q = 0; q < 4; ++q)
          wreg[q] = (kb + 1 < 4) ? *(const float4*)(rih[q] + kn)
                                 : *(const float4*)(rhh[q] + kn - 1024);
      }
      const float* xb = xs + kb * 256 + kl;
#pragma unroll
      for (int b = 0; b < 16; ++b) {
        float4 x4 = *(const float4*)(xb + b * P2);
#pragma unroll
        for (int q = 0; q < 4; ++q) {
          acc[q][b] += wc[q].x * x4.x;
          acc[q][b] += wc[q].y * x4.y;
          acc[q][b] += wc[q].z * x4.z;
          acc[q][b] += wc[q].w * x4.w;
        }
      }
    }
    __syncthreads();  // all x reads done; reuse xs as reduce buffer
    float* red = xs + wv * 4352;  // 64 outputs x pitch 68
#pragma unroll
    for (int q = 0; q < 4; ++q)
#pragma unroll
      for (int b = 0; b < 16; ++b) red[(q * 16 + b) * 68 + lane] = acc[q][b];
    __syncthreads();
    {
      const int w2 = tid >> 6, o = tid & 63;
      const float* rr = xs + w2 * 4352 + o * 68;
      float4 s4 = {0.f, 0.f, 0.f, 0.f};
#pragma unroll
      for (int i = 0; i < 16; ++i) {
        float4 v = *(const float4*)(rr + i * 4);
        s4.x += v.x; s4.y += v.y; s4.z += v.z; s4.w += v.w;
      }
      float s = s4.x + s4.y + s4.z + s4.w;
      int q = o >> 4, b = o & 15;
      int row = w2 * 1024 + d0 + q;
      s += a.bih2[row] + a.bhh2[row];
      gbuf[w2 * 4 + q][b] = s;
    }
    __syncthreads();
    if (tid < 64) {
      int dd = tid >> 4, b = tid & 15;
      int d = d0 + dd;
      float gi = gbuf[0 + dd][b], gf = gbuf[4 + dd][b];
      float gg = gbuf[8 + dd][b], go = gbuf[12 + dd][b];
      float co = a.c2[b * 1024 + d];
      float cn = fast_sig(gf) * co + fast_sig(gi) * fast_tanh(gg);
      float hn = fast_sig(go) * fast_tanh(cn);
      a.c2[b * 1024 + d] = cn;
      h2w[b * 1024 + d] = hn;
      a.X[(size_t)(s_ * 16 + b) * 1024 + d] = hn;  // h2_all
    }
  }
}

// ---- Kernel B(t): LSTM1 for step t + housekeeping (wg 256..271).
__global__ __launch_bounds__(256) void k_step_b(Args a, int t) {
  const int wg = blockIdx.x, tid = threadIdx.x;
  const int cur = t & 1, nxt = cur ^ 1;
  if (wg >= 256) {
    int b = wg - 256;
    float is = 1.f / a.sum[cur * 16 + b];
    a.cum[b * 256 + tid] += a.wexp[cur * 4096 + b * 256 + tid] * is;
    a.uctx[nxt * 4096 + b * 256 + tid] = 0.f;
    if (tid == 0) a.sum[nxt * 16 + b] = 0.f;
    return;
  }
  __shared__ __align__(16) float xs[16 * P1];  // 147,712 B
  __shared__ float gbuf[16][20];
  const float* pt = a.p + (size_t)t * 16 * 1024;
  const float* h1r = (t & 1) ? a.h1a : a.h1b;  // h1(t-1)
  float* h1w = (t & 1) ? a.h1b : a.h1a;        // h1(t)
  for (int i = tid; i < 16 * 1024; i += 256) {
    int b = i >> 10, k = i & 1023;
    xs[b * P1 + k] = pt[i];
    xs[b * P1 + 1280 + k] = h1r[i];
  }
  for (int i = tid; i < 16 * 256; i += 256) {
    int b = i >> 8, k = i & 255;
    xs[b * P1 + 1024 + k] = a.uctx[cur * 4096 + i] * (1.f / a.sum[cur * 16 + b]);
  }
  __syncthreads();
  const int wv = tid >> 6, lane = tid & 63;
  const int d0 = wg * 4;
  const int kl = lane * 4;
  const float* rih[4];
  const float* rhh[4];
#pragma unroll
  for (int q = 0; q < 4; ++q) {
    int row = wv * 1024 + d0 + q;
    rih[q] = a.Wih1 + (size_t)row * 1280;
    rhh[q] = a.Whh1 + (size_t)row * 1024;
  }
  float acc[4][16];
#pragma unroll
  for (int q = 0; q < 4; ++q)
#pragma unroll
    for (int b = 0; b < 16; ++b) acc[q][b] = 0.f;
  float4 wreg[4];
#pragma unroll
  for (int q = 0; q < 4; ++q) wreg[q] = *(const float4*)(rih[q] + kl);
  for (int kb = 0; kb < 9; ++kb) {
    float4 wc[4];
#pragma unroll
    for (int q = 0; q < 4; ++q) wc[q] = wreg[q];
    if (kb + 1 < 9) {
      int kn = (kb + 1) * 256 + kl;
#pragma unroll
      for (int q = 0; q < 4; ++q)
        wreg[q] = (kb + 1 < 5) ? *(const float4*)(rih[q] + kn)
                               : *(const float4*)(rhh[q] + kn - 1280);
    }
    const float* xb = xs + kb * 256 + kl;
#pragma unroll
    for (int b = 0; b < 16; ++b) {
      float4 x4 = *(const float4*)(xb + b * P1);
#pragma unroll
      for (int q = 0; q < 4; ++q) {
        acc[q][b] += wc[q].x * x4.x;
        acc[q][b] += wc[q].y * x4.y;
        acc[q][b] += wc[q].z * x4.z;
        acc[q][b] += wc[q].w * x4.w;
      }
    }
  }
  __syncthreads();
  float* red = xs + wv * 4352;
#pragma unroll
  for (int q = 0; q < 4; ++q)
#pragma unroll
    for (int b = 0; b < 16; ++b) red[(q * 16 + b) * 68 + lane] = acc[q][b];
  __syncthreads();
  {
    const int w2 = tid >> 6, o = tid & 63;
    const float* rr = xs + w2 * 4352 + o * 68;
    float4 s4 = {0.f, 0.f, 0.f, 0.f};
#pragma unroll
    for (int i = 0; i < 16; ++i) {
      float4 v = *(const float4*)(rr + i * 4);
      s4.x += v.x; s4.y += v.y; s4.z += v.z; s4.w += v.w;
    }
    float s = s4.x + s4.y + s4.z + s4.w;
    int q = o >> 4, b = o & 15;
    int row = w2 * 1024 + d0 + q;
    s += a.bih1[row] + a.bhh1[row];
    gbuf[w2 * 4 + q][b] = s;
  }
  __syncthreads();
  if (tid < 64) {
    int dd = tid >> 4, b = tid & 15;
    int d = d0 + dd;
    float gi = gbuf[0 + dd][b], gf = gbuf[4 + dd][b];
    float gg = gbuf[8 + dd][b], go = gbuf[12 + dd][b];
    float co = a.c1[b * 1024 + d];
    float cn = fast_sig(gf) * co + fast_sig(gi) * fast_tanh(gg);
    float hn = fast_sig(go) * fast_tanh(cn);
    a.c1[b * 1024 + d] = cn;
    h1w[b * 1024 + d] = hn;
  }
}

__global__ void k_finish(Args a) {
  int i = blockIdx.x * blockDim.x + threadIdx.x;  // tb*128+col
  if (i >= 4096 * 128) return;
  int col = i & 127, tb = i >> 7;
  int t = tb >> 4, b = tb & 15;
  float v = a.tmp[i];
  if (col < 80) a.out[(size_t)(b * 256 + t) * 80 + col] = v;
  else if (col == 80) a.out[327680 + b * 256 + t] = fast_sig(v);
}

}  // namespace

extern "C" void kernel_launch(void* const* d_in, const int* in_sizes, int n_in,
                              void* d_out, int out_size, void* d_ws, size_t ws_size,
                              hipStream_t stream) {
  float* ws = (float*)d_ws;
  Args a;
  a.enc = (const float*)d_in[0];
  a.spe = (const float*)d_in[1];
  a.mels = (const float*)d_in[2];
  a.Wpre1 = (const float*)d_in[3];  a.bpre1 = (const float*)d_in[4];
  a.Wpre2 = (const float*)d_in[5];  a.bpre2 = (const float*)d_in[6];
  a.Wsp = (const float*)d_in[7];    a.bsp = (const float*)d_in[8];
  a.Wq = (const float*)d_in[9];     a.Wm = (const float*)d_in[10];
  a.Wconv = (const float*)d_in[11]; a.Wloc = (const float*)d_in[12];
  a.vatt = (const float*)d_in[13];
  a.Wih1 = (const float*)d_in[14];  a.Whh1 = (const float*)d_in[15];
  a.bih1 = (const float*)d_in[16];  a.bhh1 = (const float*)d_in[17];
  a.Wih2 = (const float*)d_in[18];  a.Whh2 = (const float*)d_in[19];
  a.bih2 = (const float*)d_in[20];  a.bhh2 = (const float*)d_in[21];
  a.Wmel = (const float*)d_in[22];  a.bmel = (const float*)d_in[23];
  a.Wstop = (const float*)d_in[24]; a.bstop = (const float*)d_in[25];

  // ws layout (floats): total ~10.56M floats ~= 42.2 MB
  a.p       = ws + 0;         // 4096x1024
  a.X       = ws + 4194304;   // prenet hidden -> pm temp -> h2_all
  a.qp2     = ws + 8388608;   // 4096x128
  a.pm2     = ws + 8912896;   // 16x128x256
  a.prevmel = ws + 9437184;   // 4096x80
  a.h1a     = ws + 9764864;   a.h1b = ws + 9781248;
  a.c1      = ws + 9797632;
  a.h2a     = ws + 9814016;   a.h2b = ws + 9830400;
  a.c2      = ws + 9846784;
  a.cum     = ws + 9863168;   // 16x256
  a.wexp    = ws + 9867264;   // 2x16x256
  a.uctx    = ws + 9875456;   // 2x16x256
  a.sum     = ws + 9883648;   // 2x16
  a.spkvec  = ws + 9883680;   // 16x1024
  a.spkq    = ws + 9900064;   // 16x128
  a.W81     = ws + 9902112;   // 128x1024 (rows 81..127 unused)
  a.b81     = ws + 10033184;  // 128
  a.tmp     = ws + 10033312;  // 4096x128
  a.out = (float*)d_out;

  // state region zero; sum[1][*]=1.0 at offset 118800..118815
  k_init<<<(118816 + 255) / 256, 256, 0, stream>>>(ws + 9764864, 118816, 118784 + 16);
  k_prevmel<<<(TT * BB * MELD + 255) / 256, 256, 0, stream>>>(a);
  k_spkvec<<<(BB * 1024 + 255) / 256, 256, 0, stream>>>(a);
  k_spkq<<<(BB * ATTD + 255) / 256, 256, 0, stream>>>(a);
  k_prep81<<<(81 * 1024 + 255) / 256, 256, 0, stream>>>(a);

  // prenet1 -> X (temp), prenet2 -> p
  k_gemm<<<dim3(16, 32), 256, 0, stream>>>(a.prevmel, a.Wpre1, a.bpre1, a.X, 4096, 1024, 80, 1);
  k_gemm<<<dim3(16, 32), 256, 0, stream>>>(a.X, a.Wpre2, a.bpre2, a.p, 4096, 1024, 1024, 1);
  // qp2 = p @ Wq^T (+ spk @ Wq^T)
  k_gemm<<<dim3(2, 32), 256, 0, stream>>>(a.p, a.Wq, nullptr, a.qp2, 4096, 128, 1024, 0);
  k_addspkq<<<(TT * BB * ATTD + 255) / 256, 256, 0, stream>>>(a);
  // proc_mem = enc @ Wm^T -> X temp -> transpose to [b][att][l]
  k_gemm<<<dim3(2, 32), 256, 0, stream>>>(a.enc, a.Wm, nullptr, a.X, 4096, 128, 256, 0);
  k_pm_transpose<<<(BB * ATTD * LL + 255) / 256, 256, 0, stream>>>(a);

  for (int t = 0; t < 256; ++t) {
    k_step_a<<<256, 256, 0, stream>>>(a, t, 1, t > 0 ? 1 : 0);
    k_step_b<<<272, 256, 0, stream>>>(a, t);
  }
  k_step_a<<<256, 256, 0, stream>>>(a, 256, 0, 1);  // final LSTM2 for step 255

  // mel/stop projection: [4096x1024] @ W81^T -> tmp, then scatter
  k_gemm<<<dim3(2, 32), 256, 0, stream>>>(a.X, a.W81, a.b81, a.tmp, 4096, 128, 1024, 0);
  k_finish<<<(4096 * 128 + 255) / 256, 256, 0, stream>>>(a);
}